// Round 10
// baseline (452.317 us; speedup 1.0000x reference)
//
#include <hip/hip_runtime.h>
#include <hip/hip_fp16.h>

// LightGCN propagation on MI355X — round 13: single-dispatch build.
// N = 100000 nodes, D = 128, E = 2,000,000 edges, 3 layers.
//
// Round-12: spmm 71.1 us x3 (FETCH 153.8 MB, VALU 60% — mixed regime, both
// levers <10 us; frozen). Build residual 143 us vs ~50 us of traffic, and
// ~constant across all build variants since r7 -> suspect per-dispatch
// overhead + small-kernel serialization. Round 13 fuses prep+scan+part+place
// into ONE 256-block x 1024-thr kernel with a manual grid barrier
// (monotonic agent-scope counter; 256 blocks x 61 KB LDS = 1-2 blocks/CU,
// all co-resident -> spin deadlock-free). Phases:
//   A: per-chunk hist (block b) + grid-stride quant-conv
//   B: 3-step scan of ghist -> gbase (aggregate / block-0 scan / add)
//   C: deterministic partition (chunk b)
//   D: place, grid-strided over 391 buckets (LDS cache + row_ptr emit)
// Data layouts and all three spmm are byte-identical to round 12.
//
// ws layout (256 B aligned):
//   x0q/x2q, x1q : nd int8 each                  25.6 MB
//   edges, staging : E int2 each                  32 MB
//   scA, scB : n floats                          0.8 MB
//   row_ptr(n+1), ghist, gbase(+1), bsums, bar   ~1.1 MB

#define DIM  128
#define PB   256   // partition chunks
#define KPAD 512   // padded bucket count (nbuck = 391 <= 512)
#define RPB  256   // rows per bucket
#define NSCAN (KPAD * PB)     // 131072
#define NTILES (NSCAN / 1024) // 128 scan tiles
#define PCAP 7168             // place LDS edge cache (56 KB)
#define NB   256   // build grid blocks
#define NT   1024  // build block threads

static inline size_t align_up(size_t v, size_t a) { return (v + a - 1) & ~(a - 1); }

union H2 { unsigned u; __half2 h; };

__device__ __forceinline__ void gbar(int* bar, int target) {
    __syncthreads();
    if (threadIdx.x == 0) {
        __hip_atomic_fetch_add(bar, 1, __ATOMIC_ACQ_REL, __HIP_MEMORY_SCOPE_AGENT);
        while (__hip_atomic_load(bar, __ATOMIC_ACQUIRE,
                                 __HIP_MEMORY_SCOPE_AGENT) < target)
            __builtin_amdgcn_s_sleep(2);
    }
    __syncthreads();
}

// Fused build: hist+conv | scan | part | place, one dispatch.
__global__ void __launch_bounds__(1024)
lgcn_build(const float2* __restrict__ emb2, int* __restrict__ x0q,
           float* __restrict__ sc0, int n,
           const int* __restrict__ rows, const int* __restrict__ cols,
           const float* __restrict__ vals,
           int* __restrict__ ghist, int* __restrict__ gbase,
           int* __restrict__ bsums, int2* __restrict__ staging,
           int2* __restrict__ edges, int* __restrict__ row_ptr,
           int nedges, int nbuck, int* __restrict__ bar) {
    __shared__ int2 cache[PCAP];   // 56 KB (phase D)
    __shared__ int  hh[KPAD];      // 2 KB  (A: hist, C: cursors)
    __shared__ int  rcnt[RPB];
    __shared__ int  cur[RPB];
    __shared__ int  wsum[16];
    __shared__ int  wext[17];

    const int b    = blockIdx.x;
    const int tid  = threadIdx.x;
    const int lane = tid & 63;
    const int wid  = tid >> 6;
    const int chunk = (nedges + PB - 1) / PB;
    const int beg = b * chunk;
    const int end = min(beg + chunk, nedges);

    // ---- Phase A: histogram (chunk b) + quant-conv (grid-stride) ----
    for (int k = tid; k < KPAD; k += NT) hh[k] = 0;
    __syncthreads();
    for (int e = beg + tid; e < end; e += NT)
        atomicAdd(&hh[rows[e] >> 8], 1);
    // conv: one wave per row, 16 rows per block-iteration
    const int ngrp = (n + 15) >> 4;
    for (int grp = b; grp < ngrp; grp += NB) {
        const int row = grp * 16 + wid;
        if (row < n) {
            float2 v = emb2[(size_t)row * 64 + lane];
            float m = fmaxf(fabsf(v.x), fabsf(v.y));
            #pragma unroll
            for (int off = 1; off < 64; off <<= 1)
                m = fmaxf(m, __shfl_xor(m, off));
            const float inv = 127.0f / fmaxf(m, 1e-20f);
            int q0 = min(max((int)(v.x * inv + 128.5f), 0), 255);
            int q1 = min(max((int)(v.y * inv + 128.5f), 0), 255);
            ((unsigned short*)x0q)[(size_t)row * 64 + lane] =
                (unsigned short)(q0 | (q1 << 8));
            if (lane == 0) sc0[row] = m * (1.0f / 127.0f);
        }
    }
    __syncthreads();
    for (int k = tid; k < KPAD; k += NT) ghist[(k << 8) + b] = hh[k];
    gbar(bar, NB * 1);

    // ---- Phase B1: per-tile scan (blocks 0..127, 1024 elems, 1/thread) ----
    if (b < NTILES) {
        const int i0 = b * 1024 + tid;
        const int v = ghist[i0];
        int incl = v;
        #pragma unroll
        for (int off = 1; off < 64; off <<= 1) {
            int t = __shfl_up(incl, off, 64);
            if (lane >= off) incl += t;
        }
        if (lane == 63) wsum[wid] = incl;
        __syncthreads();
        if (tid == 0) {
            int r = 0;
            #pragma unroll
            for (int w = 0; w < 16; ++w) { wext[w] = r; r += wsum[w]; }
            wext[16] = r;
        }
        __syncthreads();
        gbase[i0] = wext[wid] + incl - v;
        if (tid == 0) bsums[b] = wext[16];
    }
    gbar(bar, NB * 2);

    // ---- Phase B2: block 0 scans the 128 tile sums ----
    if (b == 0) {
        int v = (tid < NTILES) ? bsums[tid] : 0;
        int incl = v;
        #pragma unroll
        for (int off = 1; off < 64; off <<= 1) {
            int t = __shfl_up(incl, off, 64);
            if (lane >= off) incl += t;
        }
        if (tid == 63) wsum[0] = incl;   // wave-0 total
        __syncthreads();
        if (tid < NTILES) {
            const int ex = incl - v + ((wid == 1) ? wsum[0] : 0);
            bsums[tid] = ex;
            if (tid == NTILES - 1) gbase[NSCAN] = ex + v;
        }
    }
    gbar(bar, NB * 3);

    // ---- Phase B3: add tile bases (blocks 0..127 cover NSCAN exactly) ----
    {
        const int i = b * 1024 + tid;
        if (i < NSCAN) gbase[i] += bsums[i >> 10];
    }
    gbar(bar, NB * 4);

    // ---- Phase C: deterministic partition (chunk b) ----
    for (int k = tid; k < KPAD; k += NT) hh[k] = gbase[(k << 8) + b];
    __syncthreads();
    for (int e = beg + tid; e < end; e += NT) {
        int r   = rows[e];
        int pos = atomicAdd(&hh[r >> 8], 1);
        staging[pos] = make_int2(cols[e] | ((r & 255) << 17),
                                 __float_as_int(vals[e] * 256.0f));
    }
    gbar(bar, NB * 5);

    // ---- Phase D: place, grid-stride over buckets ----
    for (int k = b; k < nbuck; k += NB) {
        const int base = gbase[k << 8];
        const int next = gbase[(k + 1) << 8];
        const int cnt  = next - base;
        const bool fit = (cnt <= PCAP);

        if (tid < RPB) rcnt[tid] = 0;
        __syncthreads();
        if (fit) {
            for (int i = tid; i < cnt; i += NT) {
                int2 p = staging[base + i];
                cache[i] = p;
                atomicAdd(&rcnt[(p.x >> 17) & 255], 1);
            }
        } else {
            for (int i = base + tid; i < next; i += NT)
                atomicAdd(&rcnt[(staging[i].x >> 17) & 255], 1);
        }
        __syncthreads();

        int v = (tid < RPB) ? rcnt[tid] : 0;
        int incl = v;
        #pragma unroll
        for (int off = 1; off < 64; off <<= 1) {
            int t = __shfl_up(incl, off, 64);
            if (lane >= off) incl += t;
        }
        if (wid < 4 && lane == 63) wsum[wid] = incl;
        __syncthreads();
        if (tid < RPB) {
            int woff = 0;
            #pragma unroll
            for (int w = 0; w < 4; ++w) woff += (w < wid) ? wsum[w] : 0;
            const int ex = woff + incl - v;
            cur[tid] = base + ex;
            const int r = (k << 8) + tid;
            if (r < n) row_ptr[r] = base + ex;
            if (k == nbuck - 1 && tid == 0) row_ptr[n] = next;
        }
        __syncthreads();

        if (fit) {
            for (int i = tid; i < cnt; i += NT) {
                int2 p  = cache[i];
                int pos = atomicAdd(&cur[(p.x >> 17) & 255], 1);
                edges[pos] = make_int2(p.x & 0x1FFFF, p.y);
            }
        } else {
            for (int i = base + tid; i < next; i += NT) {
                int2 p  = staging[i];
                int pos = atomicAdd(&cur[(p.x >> 17) & 255], 1);
                edges[pos] = make_int2(p.x & 0x1FFFF, p.y);
            }
        }
        __syncthreads();
    }
}

// int8-gather SpMM (byte-identical to round 12). One wave per row.
// lane = 16*g + l; g = edge slot, l = dim-eighth (8 int8 per lane).
// mode 0: quantize row -> xqout int8 + scout scale.
// mode 1: out[row] = (emb + deq(x1) + deq(x2) + s) * 0.25 (fp32)
__global__ void __launch_bounds__(256)
lgcn_spmm(const int* __restrict__ row_ptr, const int2* __restrict__ edges,
          const int2* __restrict__ xq, const float* __restrict__ scin,
          int2* __restrict__ xqout, float* __restrict__ scout,
          const float2* __restrict__ emb, const int2* __restrict__ x1q,
          const float* __restrict__ sc1, float2* __restrict__ out,
          int n, int mode) {
    const int wave = blockIdx.x * 4 + (threadIdx.x >> 6);
    const int lane = threadIdx.x & 63;
    const int g    = lane >> 4;
    const int l    = lane & 15;
    if (wave >= n) return;
    const int beg = row_ptr[wave];
    const int end = row_ptr[wave + 1];

    H2 A0, A1, A2, A3;
    A0.u = 0; A1.u = 0; A2.u = 0; A3.u = 0;
    H2 BIAS; BIAS.u = 0xE480E480;  // fp16 -1152 x2

#define QFMA8(QQ, SV)                                                         \
    {                                                                         \
        H2 hv; hv.h = __float2half2_rn(SV);                                   \
        H2 p;                                                                 \
        p.u = __builtin_amdgcn_perm(0x64646464u, (unsigned)(QQ).x, 0x05010400u); \
        A0.h = __hfma2(__hadd2(p.h, BIAS.h), hv.h, A0.h);                     \
        p.u = __builtin_amdgcn_perm(0x64646464u, (unsigned)(QQ).x, 0x05030402u); \
        A1.h = __hfma2(__hadd2(p.h, BIAS.h), hv.h, A1.h);                     \
        p.u = __builtin_amdgcn_perm(0x64646464u, (unsigned)(QQ).y, 0x05010400u); \
        A2.h = __hfma2(__hadd2(p.h, BIAS.h), hv.h, A2.h);                     \
        p.u = __builtin_amdgcn_perm(0x64646464u, (unsigned)(QQ).y, 0x05030402u); \
        A3.h = __hfma2(__hadd2(p.h, BIAS.h), hv.h, A3.h);                     \
    }

    int e = beg;
    for (; e + 16 <= end; e += 16) {
        int2 d0 = edges[e + g];
        int2 d1 = edges[e + 4 + g];
        int2 d2 = edges[e + 8 + g];
        int2 d3 = edges[e + 12 + g];
        float s0 = scin[d0.x], s1 = scin[d1.x], s2 = scin[d2.x], s3 = scin[d3.x];
        int2 q0 = xq[d0.x * 16 + l];
        int2 q1 = xq[d1.x * 16 + l];
        int2 q2 = xq[d2.x * 16 + l];
        int2 q3 = xq[d3.x * 16 + l];
        QFMA8(q0, s0 * __int_as_float(d0.y));
        QFMA8(q1, s1 * __int_as_float(d1.y));
        QFMA8(q2, s2 * __int_as_float(d2.y));
        QFMA8(q3, s3 * __int_as_float(d3.y));
    }
    for (; e + 8 <= end; e += 8) {
        int2 d0 = edges[e + g];
        int2 d1 = edges[e + 4 + g];
        float s0 = scin[d0.x], s1 = scin[d1.x];
        int2 q0 = xq[d0.x * 16 + l];
        int2 q1 = xq[d1.x * 16 + l];
        QFMA8(q0, s0 * __int_as_float(d0.y));
        QFMA8(q1, s1 * __int_as_float(d1.y));
    }
    for (; e < end; e += 4) {
        const int ee = e + g;
        int2 d = (ee < end) ? edges[ee] : make_int2(0, 0);  // val=0 -> no contrib
        float s = scin[d.x];
        int2 q = xq[d.x * 16 + l];
        QFMA8(q, s * __int_as_float(d.y));
    }
#undef QFMA8

    const float DS = 0.00390625f;  // 1/256 descale
    float2 f0 = __half22float2(A0.h), f1 = __half22float2(A1.h);
    float2 f2 = __half22float2(A2.h), f3 = __half22float2(A3.h);
    float a0 = f0.x * DS, a1 = f0.y * DS, a2 = f1.x * DS, a3 = f1.y * DS;
    float a4 = f2.x * DS, a5 = f2.y * DS, a6 = f3.x * DS, a7 = f3.y * DS;

    a0 += __shfl_xor(a0, 16); a0 += __shfl_xor(a0, 32);
    a1 += __shfl_xor(a1, 16); a1 += __shfl_xor(a1, 32);
    a2 += __shfl_xor(a2, 16); a2 += __shfl_xor(a2, 32);
    a3 += __shfl_xor(a3, 16); a3 += __shfl_xor(a3, 32);
    a4 += __shfl_xor(a4, 16); a4 += __shfl_xor(a4, 32);
    a5 += __shfl_xor(a5, 16); a5 += __shfl_xor(a5, 32);
    a6 += __shfl_xor(a6, 16); a6 += __shfl_xor(a6, 32);
    a7 += __shfl_xor(a7, 16); a7 += __shfl_xor(a7, 32);

    if (mode == 0) {
        float m = fmaxf(fmaxf(fmaxf(fabsf(a0), fabsf(a1)), fmaxf(fabsf(a2), fabsf(a3))),
                        fmaxf(fmaxf(fabsf(a4), fabsf(a5)), fmaxf(fabsf(a6), fabsf(a7))));
        m = fmaxf(m, __shfl_xor(m, 1));
        m = fmaxf(m, __shfl_xor(m, 2));
        m = fmaxf(m, __shfl_xor(m, 4));
        m = fmaxf(m, __shfl_xor(m, 8));
        const float inv = 127.0f / fmaxf(m, 1e-20f);
        int q0 = min(max((int)(a0 * inv + 128.5f), 0), 255);
        int q1 = min(max((int)(a1 * inv + 128.5f), 0), 255);
        int q2 = min(max((int)(a2 * inv + 128.5f), 0), 255);
        int q3 = min(max((int)(a3 * inv + 128.5f), 0), 255);
        int q4 = min(max((int)(a4 * inv + 128.5f), 0), 255);
        int q5 = min(max((int)(a5 * inv + 128.5f), 0), 255);
        int q6 = min(max((int)(a6 * inv + 128.5f), 0), 255);
        int q7 = min(max((int)(a7 * inv + 128.5f), 0), 255);
        if (g == 0) {
            int2 r;
            r.x = q0 | (q1 << 8) | (q2 << 16) | (q3 << 24);
            r.y = q4 | (q5 << 8) | (q6 << 16) | (q7 << 24);
            xqout[wave * 16 + l] = r;
            if (l == 0) scout[wave] = m * (1.0f / 127.0f);
        }
    } else {
        if (g == 0) {
            float4 e0 = ((const float4*)emb)[wave * 32 + l * 2 + 0];
            float4 e1 = ((const float4*)emb)[wave * 32 + l * 2 + 1];
            int2 u1 = x1q[wave * 16 + l];
            int2 u2 = xq[wave * 16 + l];
            const float s1 = sc1[wave],  o1 = -128.0f * s1;
            const float s2 = scin[wave], o2 = -128.0f * s2;
            float b0 = fmaf((float)( u1.x        & 255), s1, o1);
            float b1 = fmaf((float)((u1.x >> 8)  & 255), s1, o1);
            float b2 = fmaf((float)((u1.x >> 16) & 255), s1, o1);
            float b3 = fmaf((float)((u1.x >> 24) & 255), s1, o1);
            float b4 = fmaf((float)( u1.y        & 255), s1, o1);
            float b5 = fmaf((float)((u1.y >> 8)  & 255), s1, o1);
            float b6 = fmaf((float)((u1.y >> 16) & 255), s1, o1);
            float b7 = fmaf((float)((u1.y >> 24) & 255), s1, o1);
            float c0 = fmaf((float)( u2.x        & 255), s2, o2);
            float c1 = fmaf((float)((u2.x >> 8)  & 255), s2, o2);
            float c2 = fmaf((float)((u2.x >> 16) & 255), s2, o2);
            float c3 = fmaf((float)((u2.x >> 24) & 255), s2, o2);
            float c4 = fmaf((float)( u2.y        & 255), s2, o2);
            float c5 = fmaf((float)((u2.y >> 8)  & 255), s2, o2);
            float c6 = fmaf((float)((u2.y >> 16) & 255), s2, o2);
            float c7 = fmaf((float)((u2.y >> 24) & 255), s2, o2);
            float4 r0, r1;
            r0.x = (e0.x + b0 + c0 + a0) * 0.25f;
            r0.y = (e0.y + b1 + c1 + a1) * 0.25f;
            r0.z = (e0.z + b2 + c2 + a2) * 0.25f;
            r0.w = (e0.w + b3 + c3 + a3) * 0.25f;
            r1.x = (e1.x + b4 + c4 + a4) * 0.25f;
            r1.y = (e1.y + b5 + c5 + a5) * 0.25f;
            r1.z = (e1.z + b6 + c6 + a6) * 0.25f;
            r1.w = (e1.w + b7 + c7 + a7) * 0.25f;
            ((float4*)out)[wave * 32 + l * 2 + 0] = r0;
            ((float4*)out)[wave * 32 + l * 2 + 1] = r1;
        }
    }
}

extern "C" void kernel_launch(void* const* d_in, const int* in_sizes, int n_in,
                              void* d_out, int out_size, void* d_ws, size_t ws_size,
                              hipStream_t stream) {
    const float* emb  = (const float*)d_in[0];
    const int*   rows = (const int*)d_in[1];
    const int*   cols = (const int*)d_in[2];
    const float* vals = (const float*)d_in[3];

    const int  n_nodes = in_sizes[0] / DIM;    // 100000
    const int  nedges  = in_sizes[1];          // 2000000
    const long nd      = (long)n_nodes * DIM;  // 12.8M bytes per int8 buffer

    char* ws = (char*)d_ws;
    size_t off = 0;
    int2* bufA    = (int2*)(ws + off); off = align_up(off + (size_t)nd, 256);      // x0q then x2q
    int2* bufB    = (int2*)(ws + off); off = align_up(off + (size_t)nd, 256);      // x1q
    int2* edges   = (int2*)(ws + off); off = align_up(off + (size_t)nedges * 8, 256);
    int2* staging = (int2*)(ws + off); off = align_up(off + (size_t)nedges * 8, 256);
    float* scA    = (float*)(ws + off); off = align_up(off + (size_t)n_nodes * 4, 256);
    float* scB    = (float*)(ws + off); off = align_up(off + (size_t)n_nodes * 4, 256);
    int* row_ptr  = (int*)(ws + off);  off = align_up(off + (size_t)(n_nodes + 1) * 4, 256);
    int* ghist    = (int*)(ws + off);  off = align_up(off + (size_t)NSCAN * 4, 256);
    int* gbase    = (int*)(ws + off);  off = align_up(off + ((size_t)NSCAN + 1) * 4, 256);
    int* bsums    = (int*)(ws + off);  off = align_up(off + (size_t)NTILES * 4, 256);
    int* bar      = (int*)(ws + off);  off = align_up(off + 256, 256);
    float2* out   = (float2*)d_out;

    const int BS = 256;
    const int nbuck  = (n_nodes + RPB - 1) / RPB;  // 391 (<= KPAD)
    const int grid_s = (n_nodes + 3) / 4;          // 4 rows per block

    // single-dispatch build (hist+conv | scan | part | place)
    hipMemsetAsync(bar, 0, sizeof(int), stream);
    lgcn_build<<<NB, NT, 0, stream>>>((const float2*)emb, (int*)bufA, scA, n_nodes,
                                      rows, cols, vals, ghist, gbase, bsums,
                                      staging, edges, row_ptr, nedges, nbuck, bar);

    // 3 SpMM layers: x1 = A x0, x2 = A x1, out = (emb + x1 + x2 + A x2)/4
    lgcn_spmm<<<grid_s, BS, 0, stream>>>(row_ptr, edges, bufA, scA, bufB, scB,
                                         nullptr, nullptr, nullptr, nullptr,
                                         n_nodes, 0);
    lgcn_spmm<<<grid_s, BS, 0, stream>>>(row_ptr, edges, bufB, scB, bufA, scA,
                                         nullptr, nullptr, nullptr, nullptr,
                                         n_nodes, 0);
    lgcn_spmm<<<grid_s, BS, 0, stream>>>(row_ptr, edges, bufA, scA, nullptr, nullptr,
                                         (const float2*)emb, bufB, scB, out,
                                         n_nodes, 1);
}

// Round 11
// 408.747 us; speedup vs baseline: 1.1066x; 1.1066x over previous
//
#include <hip/hip_runtime.h>
#include <hip/hip_fp16.h>

// LightGCN propagation on MI355X — round 14: bucket scales in LDS.
// N = 100000 nodes, D = 128, E = 2,000,000 edges, 3 layers.
//
// Round-13 post-mortem: grid-barrier fused build REGRESSED (452 vs 356) —
// barrier skew + idle phases + 62KB-LDS occupancy cap. Build reverted to
// r12's 4-dispatch pipeline. New spmm analysis: TA line rate is pinned at
// ~92-95 G lines/s across r10(fp16, 8.2M lines, 86us) and r12(int8, 6.5M
// lines, 71us); the per-edge scin[col] load (random 4B, L2-hit, invisible
// in FETCH) is 1 line/edge = 1/3 of all requests. Round 14 removes it:
//   - per-256-row-BUCKET scales (391 floats = 1.6KB) cached in LDS per
//     spmm block; s = lds[col>>8] via ds_read (no TA line);
//   - mode-0 still quantizes per-row (no cross-block dependency); a tiny
//     lgcn_rescale kernel (391 blocks) bucket-maxes row scales and
//     re-grids the int8 rows; x0's rescale is fused into part's grid;
//   - spmm blocks 1024 thr (16 rows) to amortize LDS fill;
//   - error: bucket step ~1.5x row step + double-rounding -> absmax ~1e-3
//     (vs 2.6e-3 threshold).
//
// ws layout (256 B aligned):
//   x0q/x2q, x1q : nd int8 each                  25.6 MB
//   edges, staging : E int2 each                  32 MB
//   scA, scB : n floats (row scales)             0.8 MB
//   sB0/sB1/sB2 : KPAD floats (bucket scales)    6 KB
//   row_ptr(n+1), ghist, gbase(+1), tstat        ~1.5 MB

#define DIM  128
#define PB   256   // partition chunks
#define KPAD 512   // padded bucket count (nbuck = 391 <= 512)
#define RPB  256   // rows per bucket
#define NSCAN (KPAD * PB)     // 131072
#define NTILES (NSCAN / 1024) // 128 scan tiles
#define PCAP 7168             // place LDS edge cache (56 KB)

static inline size_t align_up(size_t v, size_t a) { return (v + a - 1) & ~(a - 1); }

union H2 { unsigned u; __half2 h; };

// Fused: wave-per-row quantizing conv (emb fp32 -> int8 + row scale),
// per-chunk coarse histogram, scan-status zero. 1024 threads/block.
__global__ void __launch_bounds__(1024)
lgcn_prep(const float2* __restrict__ emb2, int* __restrict__ x0q,
          float* __restrict__ sc0, int n,
          const int* __restrict__ rows, int* __restrict__ ghist, int nedges,
          unsigned long long* __restrict__ tstat) {
    __shared__ int h[KPAD];
    const int b = blockIdx.x, tid = threadIdx.x;
    if (b < PB) {
        for (int k = tid; k < KPAD; k += 1024) h[k] = 0;
        __syncthreads();
        const int chunk = (nedges + PB - 1) / PB;
        const int beg = b * chunk;
        const int end = min(beg + chunk, nedges);
        for (int e = beg + tid; e < end; e += 1024)
            atomicAdd(&h[rows[e] >> 8], 1);
        __syncthreads();
        for (int k = tid; k < KPAD; k += 1024) ghist[(k << 8) + b] = h[k];
    } else if (b == PB) {
        if (tid < NTILES) tstat[tid] = 0ull;
    } else {
        const int wid  = tid >> 6;
        const int lane = tid & 63;
        const int row  = (b - PB - 1) * 16 + wid;
        if (row >= n) return;
        float2 v = emb2[(size_t)row * 64 + lane];
        float m = fmaxf(fabsf(v.x), fabsf(v.y));
        #pragma unroll
        for (int off = 1; off < 64; off <<= 1)
            m = fmaxf(m, __shfl_xor(m, off));
        const float inv = 127.0f / fmaxf(m, 1e-20f);
        int q0 = min(max((int)(v.x * inv + 128.5f), 0), 255);
        int q1 = min(max((int)(v.y * inv + 128.5f), 0), 255);
        ((unsigned short*)x0q)[(size_t)row * 64 + lane] =
            (unsigned short)(q0 | (q1 << 8));
        if (lane == 0) sc0[row] = m * (1.0f / 127.0f);
    }
}

// Single-kernel decoupled-lookback exclusive scan of ghist -> gbase.
// (unchanged from r12; wave-parallel lookback)
__global__ void __launch_bounds__(256)
lgcn_scan(const int* __restrict__ ghist, int* __restrict__ gbase,
          unsigned long long* __restrict__ tstat, int nscan) {
    __shared__ int wsum[4];
    __shared__ int btot_s, prev_s;
    const int tile = blockIdx.x;
    const int tid  = threadIdx.x;
    const int lane = tid & 63;
    const int wid  = tid >> 6;
    const int i0   = tile * 1024 + tid * 4;

    int4 c = *(const int4*)(ghist + i0);
    const int t1 = c.x + c.y, t2 = t1 + c.z, tsum = t2 + c.w;

    int incl = tsum;
    #pragma unroll
    for (int off = 1; off < 64; off <<= 1) {
        int t = __shfl_up(incl, off, 64);
        if (lane >= off) incl += t;
    }
    if (lane == 63) wsum[wid] = incl;
    __syncthreads();
    int woff = 0;
    #pragma unroll
    for (int w = 0; w < 4; ++w) woff += (w < wid) ? wsum[w] : 0;
    const int ex = woff + incl - tsum;
    if (tid == 255) btot_s = woff + incl;
    __syncthreads();
    const int btot = btot_s;

    if (tile == 0) {
        if (tid == 0) {
            __hip_atomic_store(&tstat[0],
                (((unsigned long long)(unsigned)btot) << 32) | 2ull,
                __ATOMIC_RELEASE, __HIP_MEMORY_SCOPE_AGENT);
            prev_s = 0;
        }
    } else if (wid == 0) {
        if (lane == 0)
            __hip_atomic_store(&tstat[tile],
                (((unsigned long long)(unsigned)btot) << 32) | 1ull,
                __ATOMIC_RELEASE, __HIP_MEMORY_SCOPE_AGENT);
        int run = 0;
        int base_p = tile - 1;
        while (true) {
            const int p = base_p - lane;
            unsigned long long st;
            if (p >= 0) {
                do {
                    st = __hip_atomic_load(&tstat[p],
                        __ATOMIC_ACQUIRE, __HIP_MEMORY_SCOPE_AGENT);
                    if (((unsigned)st & 3u) != 0u) break;
                    __builtin_amdgcn_s_sleep(1);
                } while (true);
            } else {
                st = 2ull;
            }
            const unsigned f = (unsigned)st & 3u;
            const int v = (int)(unsigned)(st >> 32);
            const unsigned long long inc_mask = __ballot(f == 2u);
            int contrib;
            if (inc_mask != 0ull) {
                const int l_star = (int)(__ffsll((long long)inc_mask) - 1);
                contrib = (lane <= l_star) ? v : 0;
            } else {
                contrib = v;
            }
            #pragma unroll
            for (int off = 1; off < 64; off <<= 1)
                contrib += __shfl_xor(contrib, off);
            run += contrib;
            if (inc_mask != 0ull) break;
            base_p -= 64;
        }
        if (lane == 0) {
            __hip_atomic_store(&tstat[tile],
                (((unsigned long long)(unsigned)(run + btot)) << 32) | 2ull,
                __ATOMIC_RELEASE, __HIP_MEMORY_SCOPE_AGENT);
            prev_s = run;
        }
    }
    __syncthreads();
    const int pv = prev_s;

    int4 o;
    o.x = pv + ex;
    o.y = pv + ex + c.x;
    o.z = pv + ex + t1;
    o.w = pv + ex + t2;
    *(int4*)(gbase + i0) = o;
    if (tile == gridDim.x - 1 && tid == 255) gbase[nscan] = pv + btot;
}

// Bucket rescale: bucket-max of 256 row scales -> sB[k]; re-grid the int8
// rows from row scale to bucket scale (in-place). 1024 threads per bucket.
__device__ __forceinline__ void rescale_bucket(int k, int* __restrict__ xq,
                                               const float* __restrict__ scR,
                                               float* __restrict__ sB, int n,
                                               float* srow, float* smax) {
    const int tid = threadIdx.x;
    const int rbeg = k << 8;
    if (tid < RPB) {
        int r = rbeg + tid;
        srow[tid] = (r < n) ? scR[r] : 0.f;
    }
    __syncthreads();
    if (tid < RPB) {
        float v = srow[tid];
        #pragma unroll
        for (int off = 1; off < 64; off <<= 1) v = fmaxf(v, __shfl_xor(v, off));
        if ((tid & 63) == 0) smax[tid >> 6] = v;
    }
    __syncthreads();
    const float sBv = fmaxf(fmaxf(fmaxf(smax[0], smax[1]),
                                  fmaxf(smax[2], smax[3])), 1e-20f);
    if (tid == 0) sB[k] = sBv;
    const int row = rbeg + (tid >> 2);
    if (row >= n) return;
    const float ratio = srow[tid >> 2] / sBv;
    int4* p = (int4*)xq + (size_t)row * 8 + (size_t)(tid & 3) * 2;
    #pragma unroll
    for (int h = 0; h < 2; ++h) {
        int4 v = p[h];
        int r0 = v.x, r1 = v.y, r2 = v.z, r3 = v.w;
        int o0 = 0, o1 = 0, o2 = 0, o3 = 0;
        #pragma unroll
        for (int byt = 0; byt < 4; ++byt) {
            int b0 = (r0 >> (byt * 8)) & 255;
            int b1 = (r1 >> (byt * 8)) & 255;
            int b2 = (r2 >> (byt * 8)) & 255;
            int b3 = (r3 >> (byt * 8)) & 255;
            int n0 = min(max((int)(((float)b0 - 128.f) * ratio + 128.5f), 0), 255);
            int n1 = min(max((int)(((float)b1 - 128.f) * ratio + 128.5f), 0), 255);
            int n2 = min(max((int)(((float)b2 - 128.f) * ratio + 128.5f), 0), 255);
            int n3 = min(max((int)(((float)b3 - 128.f) * ratio + 128.5f), 0), 255);
            o0 |= n0 << (byt * 8); o1 |= n1 << (byt * 8);
            o2 |= n2 << (byt * 8); o3 |= n3 << (byt * 8);
        }
        p[h] = make_int4(o0, o1, o2, o3);
    }
}

__global__ void __launch_bounds__(1024)
lgcn_rescale(int* __restrict__ xq, const float* __restrict__ scR,
             float* __restrict__ sB, int n) {
    __shared__ float srow[RPB];
    __shared__ float smax[4];
    rescale_bucket(blockIdx.x, xq, scR, sB, n, srow, smax);
}

// Deterministic partition (chunk b); blocks >= PB run x0's bucket rescale.
__global__ void __launch_bounds__(1024)
lgcn_part(const int* __restrict__ rows, const int* __restrict__ cols,
          const float* __restrict__ vals, const int* __restrict__ gbase,
          int2* __restrict__ staging, int nedges,
          int* __restrict__ x0q, const float* __restrict__ scR,
          float* __restrict__ sB0, int n) {
    __shared__ int lcnt[KPAD];
    __shared__ float srow[RPB];
    __shared__ float smax[4];
    const int b = blockIdx.x, tid = threadIdx.x;
    if (b < PB) {
        for (int k = tid; k < KPAD; k += 1024) lcnt[k] = gbase[(k << 8) + b];
        __syncthreads();
        const int chunk = (nedges + PB - 1) / PB;
        const int beg = b * chunk;
        const int end = min(beg + chunk, nedges);
        for (int e = beg + tid; e < end; e += 1024) {
            int r   = rows[e];
            int pos = atomicAdd(&lcnt[r >> 8], 1);
            staging[pos] = make_int2(cols[e] | ((r & 255) << 17),
                                     __float_as_int(vals[e] * 256.0f));
        }
    } else {
        rescale_bucket(b - PB, x0q, scR, sB0, n, srow, smax);
    }
}

// One block per 256-row bucket (unchanged from r12).
__global__ void __launch_bounds__(1024)
lgcn_place(const int* __restrict__ gbase, const int2* __restrict__ staging,
           int* __restrict__ row_ptr, int2* __restrict__ edges, int n, int nbuck) {
    __shared__ int rcnt[RPB];
    __shared__ int cur[RPB];
    __shared__ int wsum[4];
    __shared__ int2 cache[PCAP];
    const int k    = blockIdx.x;
    const int tid  = threadIdx.x;
    const int base = gbase[k << 8];
    const int next = gbase[(k + 1) << 8];
    const int cnt  = next - base;
    const bool fit = (cnt <= PCAP);

    if (tid < RPB) rcnt[tid] = 0;
    __syncthreads();
    if (fit) {
        for (int i = tid; i < cnt; i += 1024) {
            int2 p = staging[base + i];
            cache[i] = p;
            atomicAdd(&rcnt[(p.x >> 17) & 255], 1);
        }
    } else {
        for (int i = base + tid; i < next; i += 1024)
            atomicAdd(&rcnt[(staging[i].x >> 17) & 255], 1);
    }
    __syncthreads();

    if (tid < RPB) {
        const int lane = tid & 63;
        const int wid  = tid >> 6;
        const int v = rcnt[tid];
        int incl = v;
        #pragma unroll
        for (int off = 1; off < 64; off <<= 1) {
            int t = __shfl_up(incl, off, 64);
            if (lane >= off) incl += t;
        }
        if (lane == 63) wsum[wid] = incl;
        __syncthreads();
        int woff = 0;
        #pragma unroll
        for (int w = 0; w < 4; ++w) woff += (w < wid) ? wsum[w] : 0;
        const int ex = woff + incl - v;

        cur[tid] = base + ex;
        const int r = (k << 8) + tid;
        if (r < n) row_ptr[r] = base + ex;
        if (k == gridDim.x - 1 && tid == 0) row_ptr[n] = next;
    } else {
        __syncthreads();
    }
    __syncthreads();

    if (fit) {
        for (int i = tid; i < cnt; i += 1024) {
            int2 p  = cache[i];
            int pos = atomicAdd(&cur[(p.x >> 17) & 255], 1);
            edges[pos] = make_int2(p.x & 0x1FFFF, p.y);
        }
    } else {
        for (int i = base + tid; i < next; i += 1024) {
            int2 p  = staging[i];
            int pos = atomicAdd(&cur[(p.x >> 17) & 255], 1);
            edges[pos] = make_int2(p.x & 0x1FFFF, p.y);
        }
    }
}

// int8-gather SpMM with LDS bucket scales. 1024 thr = 16 rows per block.
// lane = 16*g + l; g = edge slot, l = dim-eighth (8 int8 per lane).
// Scale lookup: s = lsc[col>>8] (ds_read, no TA line).
// mode 0: quantize row (PER-ROW scale) -> xqout + scout; rescale pass
//         converts to bucket grid afterwards.
// mode 1: out[row] = (emb + deq(x1) + deq(x2) + s) * 0.25 (fp32);
//         x1/x2 direct reads use block-uniform bucket scales.
__global__ void __launch_bounds__(1024)
lgcn_spmm(const int* __restrict__ row_ptr, const int2* __restrict__ edges,
          const int2* __restrict__ xq, const float* __restrict__ sBin,
          int2* __restrict__ xqout, float* __restrict__ scout,
          const float2* __restrict__ emb, const int2* __restrict__ x1q,
          const float* __restrict__ sB1, float2* __restrict__ out,
          int n, int mode) {
    __shared__ float lsc[KPAD];
    __shared__ float lsc1[KPAD];
    const int tid = threadIdx.x;
    for (int i = tid; i < KPAD; i += 1024) {
        lsc[i] = sBin[i];
        if (mode != 0) lsc1[i] = sB1[i];
    }
    __syncthreads();

    const int wave = blockIdx.x * 16 + (tid >> 6);
    const int lane = tid & 63;
    const int g    = lane >> 4;
    const int l    = lane & 15;
    if (wave >= n) return;
    const int beg = row_ptr[wave];
    const int end = row_ptr[wave + 1];

    H2 A0, A1, A2, A3;
    A0.u = 0; A1.u = 0; A2.u = 0; A3.u = 0;
    H2 BIAS; BIAS.u = 0xE480E480;  // fp16 -1152 x2

#define QFMA8(QQ, SV)                                                         \
    {                                                                         \
        H2 hv; hv.h = __float2half2_rn(SV);                                   \
        H2 p;                                                                 \
        p.u = __builtin_amdgcn_perm(0x64646464u, (unsigned)(QQ).x, 0x05010400u); \
        A0.h = __hfma2(__hadd2(p.h, BIAS.h), hv.h, A0.h);                     \
        p.u = __builtin_amdgcn_perm(0x64646464u, (unsigned)(QQ).x, 0x05030402u); \
        A1.h = __hfma2(__hadd2(p.h, BIAS.h), hv.h, A1.h);                     \
        p.u = __builtin_amdgcn_perm(0x64646464u, (unsigned)(QQ).y, 0x05010400u); \
        A2.h = __hfma2(__hadd2(p.h, BIAS.h), hv.h, A2.h);                     \
        p.u = __builtin_amdgcn_perm(0x64646464u, (unsigned)(QQ).y, 0x05030402u); \
        A3.h = __hfma2(__hadd2(p.h, BIAS.h), hv.h, A3.h);                     \
    }

    int e = beg;
    for (; e + 16 <= end; e += 16) {
        int2 d0 = edges[e + g];
        int2 d1 = edges[e + 4 + g];
        int2 d2 = edges[e + 8 + g];
        int2 d3 = edges[e + 12 + g];
        float s0 = lsc[d0.x >> 8], s1 = lsc[d1.x >> 8];
        float s2 = lsc[d2.x >> 8], s3 = lsc[d3.x >> 8];
        int2 q0 = xq[d0.x * 16 + l];
        int2 q1 = xq[d1.x * 16 + l];
        int2 q2 = xq[d2.x * 16 + l];
        int2 q3 = xq[d3.x * 16 + l];
        QFMA8(q0, s0 * __int_as_float(d0.y));
        QFMA8(q1, s1 * __int_as_float(d1.y));
        QFMA8(q2, s2 * __int_as_float(d2.y));
        QFMA8(q3, s3 * __int_as_float(d3.y));
    }
    for (; e + 8 <= end; e += 8) {
        int2 d0 = edges[e + g];
        int2 d1 = edges[e + 4 + g];
        float s0 = lsc[d0.x >> 8], s1 = lsc[d1.x >> 8];
        int2 q0 = xq[d0.x * 16 + l];
        int2 q1 = xq[d1.x * 16 + l];
        QFMA8(q0, s0 * __int_as_float(d0.y));
        QFMA8(q1, s1 * __int_as_float(d1.y));
    }
    for (; e < end; e += 4) {
        const int ee = e + g;
        int2 d = (ee < end) ? edges[ee] : make_int2(0, 0);  // val=0 -> no contrib
        float s = lsc[d.x >> 8];
        int2 q = xq[d.x * 16 + l];
        QFMA8(q, s * __int_as_float(d.y));
    }
#undef QFMA8

    const float DS = 0.00390625f;  // 1/256 descale
    float2 f0 = __half22float2(A0.h), f1 = __half22float2(A1.h);
    float2 f2 = __half22float2(A2.h), f3 = __half22float2(A3.h);
    float a0 = f0.x * DS, a1 = f0.y * DS, a2 = f1.x * DS, a3 = f1.y * DS;
    float a4 = f2.x * DS, a5 = f2.y * DS, a6 = f3.x * DS, a7 = f3.y * DS;

    a0 += __shfl_xor(a0, 16); a0 += __shfl_xor(a0, 32);
    a1 += __shfl_xor(a1, 16); a1 += __shfl_xor(a1, 32);
    a2 += __shfl_xor(a2, 16); a2 += __shfl_xor(a2, 32);
    a3 += __shfl_xor(a3, 16); a3 += __shfl_xor(a3, 32);
    a4 += __shfl_xor(a4, 16); a4 += __shfl_xor(a4, 32);
    a5 += __shfl_xor(a5, 16); a5 += __shfl_xor(a5, 32);
    a6 += __shfl_xor(a6, 16); a6 += __shfl_xor(a6, 32);
    a7 += __shfl_xor(a7, 16); a7 += __shfl_xor(a7, 32);

    if (mode == 0) {
        float m = fmaxf(fmaxf(fmaxf(fabsf(a0), fabsf(a1)), fmaxf(fabsf(a2), fabsf(a3))),
                        fmaxf(fmaxf(fabsf(a4), fabsf(a5)), fmaxf(fabsf(a6), fabsf(a7))));
        m = fmaxf(m, __shfl_xor(m, 1));
        m = fmaxf(m, __shfl_xor(m, 2));
        m = fmaxf(m, __shfl_xor(m, 4));
        m = fmaxf(m, __shfl_xor(m, 8));
        const float inv = 127.0f / fmaxf(m, 1e-20f);
        int q0 = min(max((int)(a0 * inv + 128.5f), 0), 255);
        int q1 = min(max((int)(a1 * inv + 128.5f), 0), 255);
        int q2 = min(max((int)(a2 * inv + 128.5f), 0), 255);
        int q3 = min(max((int)(a3 * inv + 128.5f), 0), 255);
        int q4 = min(max((int)(a4 * inv + 128.5f), 0), 255);
        int q5 = min(max((int)(a5 * inv + 128.5f), 0), 255);
        int q6 = min(max((int)(a6 * inv + 128.5f), 0), 255);
        int q7 = min(max((int)(a7 * inv + 128.5f), 0), 255);
        if (g == 0) {
            int2 r;
            r.x = q0 | (q1 << 8) | (q2 << 16) | (q3 << 24);
            r.y = q4 | (q5 << 8) | (q6 << 16) | (q7 << 24);
            xqout[wave * 16 + l] = r;
            if (l == 0) scout[wave] = m * (1.0f / 127.0f);
        }
    } else {
        if (g == 0) {
            float4 e0 = ((const float4*)emb)[wave * 32 + l * 2 + 0];
            float4 e1 = ((const float4*)emb)[wave * 32 + l * 2 + 1];
            int2 u1 = x1q[wave * 16 + l];
            int2 u2 = xq[wave * 16 + l];
            const float s1 = lsc1[wave >> 8], o1 = -128.0f * s1;
            const float s2 = lsc[wave >> 8],  o2 = -128.0f * s2;
            float b0 = fmaf((float)( u1.x        & 255), s1, o1);
            float b1 = fmaf((float)((u1.x >> 8)  & 255), s1, o1);
            float b2 = fmaf((float)((u1.x >> 16) & 255), s1, o1);
            float b3 = fmaf((float)((u1.x >> 24) & 255), s1, o1);
            float b4 = fmaf((float)( u1.y        & 255), s1, o1);
            float b5 = fmaf((float)((u1.y >> 8)  & 255), s1, o1);
            float b6 = fmaf((float)((u1.y >> 16) & 255), s1, o1);
            float b7 = fmaf((float)((u1.y >> 24) & 255), s1, o1);
            float c0 = fmaf((float)( u2.x        & 255), s2, o2);
            float c1 = fmaf((float)((u2.x >> 8)  & 255), s2, o2);
            float c2 = fmaf((float)((u2.x >> 16) & 255), s2, o2);
            float c3 = fmaf((float)((u2.x >> 24) & 255), s2, o2);
            float c4 = fmaf((float)( u2.y        & 255), s2, o2);
            float c5 = fmaf((float)((u2.y >> 8)  & 255), s2, o2);
            float c6 = fmaf((float)((u2.y >> 16) & 255), s2, o2);
            float c7 = fmaf((float)((u2.y >> 24) & 255), s2, o2);
            float4 r0, r1;
            r0.x = (e0.x + b0 + c0 + a0) * 0.25f;
            r0.y = (e0.y + b1 + c1 + a1) * 0.25f;
            r0.z = (e0.z + b2 + c2 + a2) * 0.25f;
            r0.w = (e0.w + b3 + c3 + a3) * 0.25f;
            r1.x = (e1.x + b4 + c4 + a4) * 0.25f;
            r1.y = (e1.y + b5 + c5 + a5) * 0.25f;
            r1.z = (e1.z + b6 + c6 + a6) * 0.25f;
            r1.w = (e1.w + b7 + c7 + a7) * 0.25f;
            ((float4*)out)[wave * 32 + l * 2 + 0] = r0;
            ((float4*)out)[wave * 32 + l * 2 + 1] = r1;
        }
    }
}

extern "C" void kernel_launch(void* const* d_in, const int* in_sizes, int n_in,
                              void* d_out, int out_size, void* d_ws, size_t ws_size,
                              hipStream_t stream) {
    const float* emb  = (const float*)d_in[0];
    const int*   rows = (const int*)d_in[1];
    const int*   cols = (const int*)d_in[2];
    const float* vals = (const float*)d_in[3];

    const int  n_nodes = in_sizes[0] / DIM;    // 100000
    const int  nedges  = in_sizes[1];          // 2000000
    const long nd      = (long)n_nodes * DIM;  // 12.8M bytes per int8 buffer

    char* ws = (char*)d_ws;
    size_t off = 0;
    int2* bufA    = (int2*)(ws + off); off = align_up(off + (size_t)nd, 256);      // x0q then x2q
    int2* bufB    = (int2*)(ws + off); off = align_up(off + (size_t)nd, 256);      // x1q
    int2* edges   = (int2*)(ws + off); off = align_up(off + (size_t)nedges * 8, 256);
    int2* staging = (int2*)(ws + off); off = align_up(off + (size_t)nedges * 8, 256);
    float* scA    = (float*)(ws + off); off = align_up(off + (size_t)n_nodes * 4, 256);
    float* scB    = (float*)(ws + off); off = align_up(off + (size_t)n_nodes * 4, 256);
    float* sB0    = (float*)(ws + off); off = align_up(off + (size_t)KPAD * 4, 256);
    float* sB1    = (float*)(ws + off); off = align_up(off + (size_t)KPAD * 4, 256);
    float* sB2    = (float*)(ws + off); off = align_up(off + (size_t)KPAD * 4, 256);
    int* row_ptr  = (int*)(ws + off);  off = align_up(off + (size_t)(n_nodes + 1) * 4, 256);
    int* ghist    = (int*)(ws + off);  off = align_up(off + (size_t)NSCAN * 4, 256);
    int* gbase    = (int*)(ws + off);  off = align_up(off + ((size_t)NSCAN + 1) * 4, 256);
    unsigned long long* tstat = (unsigned long long*)(ws + off);
    off = align_up(off + (size_t)NTILES * 8, 256);
    float2* out   = (float2*)d_out;

    const int nbuck   = (n_nodes + RPB - 1) / RPB;        // 391 (<= KPAD)
    const int grid_c  = (n_nodes + 15) / 16;              // conv rows, 16/block
    const int grid_s  = (n_nodes + 15) / 16;              // 16 rows per spmm block

    // quant-conv + histogram + scan-status zero
    lgcn_prep<<<PB + 1 + grid_c, 1024, 0, stream>>>((const float2*)emb, (int*)bufA,
                                                    scA, n_nodes, rows, ghist,
                                                    nedges, tstat);
    // decoupled-lookback scan
    lgcn_scan<<<NTILES, 256, 0, stream>>>(ghist, gbase, tstat, NSCAN);
    // partition (+ fused x0 bucket-rescale) and place
    lgcn_part<<<PB + nbuck, 1024, 0, stream>>>(rows, cols, vals, gbase, staging,
                                               nedges, (int*)bufA, scA, sB0, n_nodes);
    lgcn_place<<<nbuck, 1024, 0, stream>>>(gbase, staging, row_ptr, edges,
                                           n_nodes, nbuck);

    // 3 SpMM layers with bucket-rescale between: x1 = A x0, x2 = A x1,
    // out = (emb + x1 + x2 + A x2)/4
    lgcn_spmm<<<grid_s, 1024, 0, stream>>>(row_ptr, edges, bufA, sB0, bufB, scB,
                                           nullptr, nullptr, nullptr, nullptr,
                                           n_nodes, 0);
    lgcn_rescale<<<nbuck, 1024, 0, stream>>>((int*)bufB, scB, sB1, n_nodes);
    lgcn_spmm<<<grid_s, 1024, 0, stream>>>(row_ptr, edges, bufB, sB1, bufA, scA,
                                           nullptr, nullptr, nullptr, nullptr,
                                           n_nodes, 0);
    lgcn_rescale<<<nbuck, 1024, 0, stream>>>((int*)bufA, scA, sB2, n_nodes);
    lgcn_spmm<<<grid_s, 1024, 0, stream>>>(row_ptr, edges, bufA, sB2, nullptr,
                                           nullptr, (const float2*)emb, bufB,
                                           sB1, out, n_nodes, 1);
}